// Round 3
// baseline (283.680 us; speedup 1.0000x reference)
//
#include <hip/hip_runtime.h>

// GaborLayer: out[p][o] = sin(x[p]·W[o] + b[o]) * exp(-0.5*gamma[o]*||x[p]-mu[o]||^2)
// P = 262144 points, OUT = 256, IN = 3. Output = 256 MiB fp32 -> write-BW bound.
//
// R3: evidence from R1/R2 (identical bench despite restructure) says the bench
// time is dominated by harness fill/restore work; the kernel portion is ~50-75us
// vs a ~45us write floor. This version minimizes VGPR pressure (no point unroll,
// constants loaded via coalesced float4) to rule out scratch spills, keeps
// nontemporal float4 stores, and relies on 16K waves for latency hiding.

#define OUT_F 256

typedef float v4f __attribute__((ext_vector_type(4)));

__global__ __launch_bounds__(256, 4) void gabor_kernel(
    const float* __restrict__ x,      // (P, 3)
    const float* __restrict__ W,      // (256, 3)
    const float* __restrict__ b,      // (256,)
    const float* __restrict__ mu,     // (256, 3)
    const float* __restrict__ gamma,  // (256,)
    float* __restrict__ out,          // (P, 256)
    int P)
{
    const int lane        = threadIdx.x & 63;
    const int waveInBlock = threadIdx.x >> 6;
    const int wavesPerBlk = blockDim.x >> 6;
    const int wavesTotal  = gridDim.x * wavesPerBlk;
    const int waveId      = blockIdx.x * wavesPerBlk + waveInBlock;

    const int o = lane << 2;  // features [4*lane, 4*lane+3]

    // Coalesced constant loads: lane's 4 features occupy 12 contiguous floats
    // of W (and mu), 4 contiguous floats of b/gamma. 16B-aligned per lane.
    float wv[12], mv[12];
    {
        const v4f* Wp = (const v4f*)(W + o * 3);
        const v4f* Mp = (const v4f*)(mu + o * 3);
#pragma unroll
        for (int i = 0; i < 3; ++i) {
            v4f wq = Wp[i], mq = Mp[i];
#pragma unroll
            for (int j = 0; j < 4; ++j) { wv[i * 4 + j] = wq[j]; mv[i * 4 + j] = mq[j]; }
        }
    }
    const v4f bq = *(const v4f*)(b + o);
    const v4f gq = *(const v4f*)(gamma + o);

    float bb[4], gs[4], mu2s[4];
#pragma unroll
    for (int j = 0; j < 4; ++j) {
        bb[j] = bq[j];
        gs[j] = -0.5f * gq[j];
        mu2s[j] = mv[j * 3] * mv[j * 3] + mv[j * 3 + 1] * mv[j * 3 + 1] + mv[j * 3 + 2] * mv[j * 3 + 2];
    }

    for (int p = waveId; p < P; p += wavesTotal) {
        // Wave-uniform scalar loads (lgkmcnt path, decoupled from store vmcnt).
        const int ps = __builtin_amdgcn_readfirstlane(p);
        const float x0 = x[ps * 3 + 0];
        const float x1 = x[ps * 3 + 1];
        const float x2 = x[ps * 3 + 2];
        const float xs = x0 * x0 + x1 * x1 + x2 * x2;

        v4f r;
#pragma unroll
        for (int j = 0; j < 4; ++j) {
            const float lin   = fmaf(wv[j * 3], x0, fmaf(wv[j * 3 + 1], x1, fmaf(wv[j * 3 + 2], x2, bb[j])));
            const float cross = fmaf(mv[j * 3], x0, fmaf(mv[j * 3 + 1], x1, mv[j * 3 + 2] * x2));
            const float D     = xs - 2.0f * cross + mu2s[j];   // reference identity
            r[j] = __sinf(lin) * __expf(gs[j] * D);
        }
        __builtin_nontemporal_store(r, (v4f*)(out + (size_t)p * OUT_F + o));
    }
}

extern "C" void kernel_launch(void* const* d_in, const int* in_sizes, int n_in,
                              void* d_out, int out_size, void* d_ws, size_t ws_size,
                              hipStream_t stream) {
    const float* x     = (const float*)d_in[0];
    const float* W     = (const float*)d_in[1];
    const float* b     = (const float*)d_in[2];
    const float* mu    = (const float*)d_in[3];
    const float* gamma = (const float*)d_in[4];
    float* out = (float*)d_out;

    const int P = in_sizes[0] / 3;  // B*N points

    // 4096 blocks x 4 waves = 16384 waves -> 16 points per wave, interleaved
    // stride keeps stores spread across all channels the whole time.
    gabor_kernel<<<4096, 256, 0, stream>>>(x, W, b, mu, gamma, out, P);
}